// Round 1
// baseline (260.785 us; speedup 1.0000x reference)
//
#include <hip/hip_runtime.h>

// TreeSoftDiceLoss collapses algebraically:
//   log_softmax(x) <= 0 everywhere  ->  clip(.,1e-7,0.9999999) == 1e-7 everywhere
//   (level matrices only SUM nonpositive channels, so both levels identical)
// Therefore only the per-class pixel counts of `targets` matter:
//   inter_c = 1e-7*count_c ; card_c = 1e-7*B*N + count_c
//   dice_c  = (2*inter_c + 1)/(card_c + 1 + 1e-7) ; loss = mean_c (1-dice_c)*[count_c>0]
//   out = [2*L, L, L]
// The logits input (113 MB) is dead; we only histogram targets (37.7 MB).

__global__ void tsd_hist_kernel(const int* __restrict__ t, long long n,
                                unsigned long long* __restrict__ cnt) {
    long long n4 = n >> 2;  // number of int4 groups
    long long tid = (long long)blockIdx.x * blockDim.x + threadIdx.x;
    long long stride = (long long)gridDim.x * blockDim.x;

    unsigned int c1 = 0, c2 = 0;
    const int4* t4 = (const int4*)t;
    for (long long j = tid; j < n4; j += stride) {
        int4 v = t4[j];
        c1 += (unsigned)(v.x == 1) + (unsigned)(v.y == 1) +
              (unsigned)(v.z == 1) + (unsigned)(v.w == 1);
        c2 += (unsigned)(v.x == 2) + (unsigned)(v.y == 2) +
              (unsigned)(v.z == 2) + (unsigned)(v.w == 2);
    }
    // scalar tail (n not multiple of 4)
    long long tail_start = n4 << 2;
    for (long long j = tail_start + tid; j < n; j += stride) {
        int v = t[j];
        c1 += (unsigned)(v == 1);
        c2 += (unsigned)(v == 2);
    }

    // wave-64 butterfly reduction
    #pragma unroll
    for (int off = 32; off > 0; off >>= 1) {
        c1 += __shfl_down(c1, off, 64);
        c2 += __shfl_down(c2, off, 64);
    }
    if ((threadIdx.x & 63) == 0) {
        atomicAdd(&cnt[0], (unsigned long long)c1);
        atomicAdd(&cnt[1], (unsigned long long)c2);
    }
}

__global__ void tsd_finalize_kernel(const unsigned long long* __restrict__ cnt,
                                    float* __restrict__ out, long long P) {
    if (threadIdx.x != 0 || blockIdx.x != 0) return;
    double c1 = (double)cnt[0];
    double c2 = (double)cnt[1];
    double c0 = (double)P - c1 - c2;
    double counts[3] = {c0, c1, c2};
    const double SP = 1e-7;        // clipped log-softmax value, everywhere
    const double BN = (double)P;   // B * H * W  (total pixels)
    double level = 0.0;
    #pragma unroll
    for (int c = 0; c < 3; ++c) {
        double inter = SP * counts[c];
        double card  = SP * BN + counts[c];
        double dice  = (2.0 * inter + 1.0) / (card + 1.0 + 1e-7);
        double loss  = 1.0 - dice;
        if (counts[c] > 0.0) level += loss;
    }
    level *= (1.0 / 3.0);
    out[0] = (float)(2.0 * level);  // total
    out[1] = (float)level;          // level 0 loss
    out[2] = (float)level;          // level 1 loss
}

extern "C" void kernel_launch(void* const* d_in, const int* in_sizes, int n_in,
                              void* d_out, int out_size, void* d_ws, size_t ws_size,
                              hipStream_t stream) {
    // inputs: d_in[0] = logits fp32 (unused), d_in[1] = targets int32
    const int* targets = (const int*)d_in[1];
    long long P = (long long)in_sizes[1];
    float* out = (float*)d_out;
    unsigned long long* cnt = (unsigned long long*)d_ws;

    hipMemsetAsync(cnt, 0, 2 * sizeof(unsigned long long), stream);

    const int block = 256;
    long long n4 = P >> 2;
    int grid = (int)((n4 + block - 1) / block);
    if (grid > 1024) grid = 1024;
    if (grid < 1) grid = 1;
    tsd_hist_kernel<<<grid, block, 0, stream>>>(targets, P, cnt);
    tsd_finalize_kernel<<<1, 64, 0, stream>>>(cnt, out, P);
}

// Round 2
// 163.388 us; speedup vs baseline: 1.5961x; 1.5961x over previous
//
#include <hip/hip_runtime.h>

// TreeSoftDiceLoss collapses algebraically:
//   log_softmax(x) <= 0 everywhere -> clip(.,1e-7,0.9999999) == 1e-7 everywhere
//   (level matrices only SUM nonpositive channels, so both levels identical).
// Only the per-class pixel counts of `targets` matter:
//   inter_c = 1e-7*count_c ; card_c = 1e-7*B*N + count_c
//   dice_c  = (2*inter_c + 1)/(card_c + 1 + 1e-7) ; L = mean_c (1-dice_c)*[count_c>0]
//   out = [2*L, L, L]
// R1 lesson: same-address device-scope atomics cost ~13ns each serialized
// cross-XCD (8192 of them = 111us). This version uses ZERO global atomics:
// block-level reduction -> plain uint2 store per block -> tiny reduce kernel.

#define HIST_BLOCKS 2048
#define HIST_THREADS 256

__global__ __launch_bounds__(HIST_THREADS) void tsd_hist_kernel(
    const int* __restrict__ t, long long n, uint2* __restrict__ partials) {
    long long n4 = n >> 2;
    long long tid = (long long)blockIdx.x * blockDim.x + threadIdx.x;
    long long stride = (long long)gridDim.x * blockDim.x;

    unsigned int c1 = 0, c2 = 0;
    const int4* t4 = (const int4*)t;
    for (long long j = tid; j < n4; j += stride) {
        int4 v = t4[j];
        c1 += (unsigned)(v.x == 1) + (unsigned)(v.y == 1) +
              (unsigned)(v.z == 1) + (unsigned)(v.w == 1);
        c2 += (unsigned)(v.x == 2) + (unsigned)(v.y == 2) +
              (unsigned)(v.z == 2) + (unsigned)(v.w == 2);
    }
    // scalar tail (empty when n % 4 == 0, as here)
    for (long long j = (n4 << 2) + tid; j < n; j += stride) {
        int v = t[j];
        c1 += (unsigned)(v == 1);
        c2 += (unsigned)(v == 2);
    }

    // wave-64 reduction
    #pragma unroll
    for (int off = 32; off > 0; off >>= 1) {
        c1 += __shfl_down(c1, off, 64);
        c2 += __shfl_down(c2, off, 64);
    }

    __shared__ uint2 ws[HIST_THREADS / 64];
    int lane = threadIdx.x & 63;
    int wave = threadIdx.x >> 6;
    if (lane == 0) ws[wave] = make_uint2(c1, c2);
    __syncthreads();
    if (threadIdx.x == 0) {
        unsigned a = 0, b = 0;
        #pragma unroll
        for (int w = 0; w < HIST_THREADS / 64; ++w) { a += ws[w].x; b += ws[w].y; }
        partials[blockIdx.x] = make_uint2(a, b);
    }
}

__global__ __launch_bounds__(256) void tsd_finalize_kernel(
    const uint2* __restrict__ partials, int num_partials,
    float* __restrict__ out, long long P) {
    unsigned int c1 = 0, c2 = 0;
    for (int i = threadIdx.x; i < num_partials; i += 256) {
        uint2 p = partials[i];
        c1 += p.x;
        c2 += p.y;
    }
    #pragma unroll
    for (int off = 32; off > 0; off >>= 1) {
        c1 += __shfl_down(c1, off, 64);
        c2 += __shfl_down(c2, off, 64);
    }
    __shared__ uint2 ws[4];
    int lane = threadIdx.x & 63;
    int wave = threadIdx.x >> 6;
    if (lane == 0) ws[wave] = make_uint2(c1, c2);
    __syncthreads();
    if (threadIdx.x == 0) {
        double d1 = 0.0, d2 = 0.0;
        #pragma unroll
        for (int w = 0; w < 4; ++w) { d1 += ws[w].x; d2 += ws[w].y; }
        double d0 = (double)P - d1 - d2;
        double counts[3] = {d0, d1, d2};
        const double SP = 1e-7;      // clipped log-softmax value, everywhere
        const double BN = (double)P; // total pixels across batch
        double level = 0.0;
        #pragma unroll
        for (int c = 0; c < 3; ++c) {
            double inter = SP * counts[c];
            double card  = SP * BN + counts[c];
            double dice  = (2.0 * inter + 1.0) / (card + 1.0 + 1e-7);
            if (counts[c] > 0.0) level += 1.0 - dice;
        }
        level *= (1.0 / 3.0);
        out[0] = (float)(2.0 * level);
        out[1] = (float)level;
        out[2] = (float)level;
    }
}

extern "C" void kernel_launch(void* const* d_in, const int* in_sizes, int n_in,
                              void* d_out, int out_size, void* d_ws, size_t ws_size,
                              hipStream_t stream) {
    // inputs: d_in[0] = logits fp32 (dead), d_in[1] = targets int32
    const int* targets = (const int*)d_in[1];
    long long P = (long long)in_sizes[1];
    float* out = (float*)d_out;
    uint2* partials = (uint2*)d_ws;  // HIST_BLOCKS * 8 bytes, fully overwritten

    tsd_hist_kernel<<<HIST_BLOCKS, HIST_THREADS, 0, stream>>>(targets, P, partials);
    tsd_finalize_kernel<<<1, 256, 0, stream>>>(partials, HIST_BLOCKS, out, P);
}